// Round 8
// baseline (151.753 us; speedup 1.0000x reference)
//
#include <hip/hip_runtime.h>
#include <hip/hip_bf16.h>

// Problem dims (fixed): B=2, N=1024, SR=1, S=seq_in*nh_in=64, NV=4, NC=32,
// NLON=NLAT=4 -> NJ=16 basis pairs. NWIN = B*N = 2048.
#define NWIN 2048
#define SDIM 64
#define NJ 16

__device__ __forceinline__ float bf2f(unsigned int u16) {
    union { unsigned int i; float f; } v;
    v.i = u16 << 16;
    return v.f;
}

__device__ __forceinline__ int bf16ish(unsigned int w) {
    const int e = (w >> 7) & 0xFF;   // exponent of the LOW u16 viewed as bf16
    return (e >= 102 && e <= 134) ? 1 : 0;
}

// dtype probe: low u16 of 16 consecutive dwords (= even elements 0,2,..,30).
// bf16 N(0,1) exponents land in [102,134]; f32 storage puts uniform mantissa
// bits there (P~0.13/word). 16-word vote -> P(err) ~ 1e-12.
__device__ __forceinline__ bool probe_bf16(const void* p) {
    const uint4* q = (const uint4*)p;
    int v = 0;
#pragma unroll
    for (int i = 0; i < 4; ++i) {
        const uint4 w = q[i];
        v += bf16ish(w.x); v += bf16ish(w.y);
        v += bf16ish(w.z); v += bf16ish(w.w);
    }
    return v >= 12;
}

// R8. Evidence-driven structure:
//  - allocator pins 64 VGPRs and spills excess (R4/R6: VGPR_Count=64 +
//    WRITE 5-10x ideal) -> keep live set < 64: acc[16][2] + 8 pending loads.
//  - runtime-indexed register arrays -> scratch (R4/R5) -> static idx only.
//  - R3/R7 kernels ~35us vs 8.3us HBM floor (overhead fit via R4/R6):
//    exposed global latency. Fix: x-loads are phase-1-independent, so issue
//    batch 1 (8 dwords) BEFORE the barrier (drains under phase-1 exp/
//    butterfly), batch 2 right after (hides under first 8 FMA iters).
//  - one barrier total; x-probe per-thread (uniform, 4 uint4 loads);
//    coords/params probes in wave 0 only.
// Dtypes (R1-R7): x bf16, coords/params/out f32. Probes retained.
__global__ __launch_bounds__(256, 4) void gauss_agg_kernel(
    const void* __restrict__ x,       // (NWIN, S, NV=4, NC=32)
    const void* __restrict__ clon,    // (NWIN, S)
    const void* __restrict__ clat,    // (NWIN, S)
    const void* __restrict__ mlon,    // (4)
    const void* __restrict__ mlat,    // (4)
    const void* __restrict__ sigma,   // (1)
    float* __restrict__ out)          // (NWIN, NV, NJ, NC) f32
{
    __shared__ alignas(16) float s_wlon[SDIM][4];
    __shared__ alignas(16) float s_wlat[SDIM][4];
    __shared__ float s_sinv[NJ];

    const int tid  = threadIdx.x;
    const int win  = blockIdx.x;
    const int v    = tid >> 6;      // variable 0..3 (one per wave)
    const int lane = tid & 63;
    const int sh   = lane >> 4;     // s-phase 0..3: s = 4*it + sh
    const int c2   = lane & 15;     // channel pair (c = 2*c2, 2*c2+1)

    // x dtype (grid-uniform result; every thread computes it -> no barrier)
    const bool xb = probe_bf16(x);

    // ---- prefetch batch 1: first 8 of 16 x loads, BEFORE the barrier ----
    // 2-ch units: index = win*4096 + s*64 + v*16 + c2  (uint=2 bf16 / float2)
    const size_t base = (size_t)win * 4096 + v * 16 + c2;
    unsigned int ua[8];
    float2 fa[8];
    if (xb) {
        const unsigned int* xp = (const unsigned int*)x + base;
#pragma unroll
        for (int it = 0; it < 8; ++it) ua[it] = xp[(size_t)(4 * it + sh) * 64];
    } else {
        const float2* xp = (const float2*)x + base;
#pragma unroll
        for (int it = 0; it < 8; ++it) fa[it] = xp[(size_t)(4 * it + sh) * 64];
    }

    // ---------------- phase 1: weights (wave 0, lane == s) ----------------
    if (tid < 64) {
        const bool cb = probe_bf16(clon);
        const bool mb = ((const unsigned short*)mlon)[0] != 0;
        const bool sb = ((const unsigned short*)sigma)[0] != 0;

        const float sigraw = sb ? bf2f(((const unsigned short*)sigma)[0])
                                : ((const float*)sigma)[0];
        const float inv = 1.0f / fmaxf(sigraw, 1e-10f);

        float mlo[4], mla[4];
#pragma unroll
        for (int l = 0; l < 4; ++l) {
            mlo[l] = mb ? bf2f(((const unsigned short*)mlon)[l])
                        : ((const float*)mlon)[l];
            mla[l] = mb ? bf2f(((const unsigned short*)mlat)[l])
                        : ((const float*)mlat)[l];
        }

        float lon, lat;
        if (cb) {
            lon = bf2f(((const unsigned short*)clon)[win * SDIM + tid]);
            lat = bf2f(((const unsigned short*)clat)[win * SDIM + tid]);
        } else {
            lon = ((const float*)clon)[win * SDIM + tid];
            lat = ((const float*)clat)[win * SDIM + tid];
        }

        float wlon[4], wlat[4];
#pragma unroll
        for (int l = 0; l < 4; ++l) {
            const float dlo = (lon - mlo[l]) * inv;
            wlon[l] = __expf(-0.5f * dlo * dlo);
            const float dla = (lat - mla[l]) * inv;
            wlat[l] = __expf(-0.5f * dla * dla);
        }
        *reinterpret_cast<float4*>(&s_wlon[tid][0]) =
            make_float4(wlon[0], wlon[1], wlon[2], wlon[3]);
        *reinterpret_cast<float4*>(&s_wlat[tid][0]) =
            make_float4(wlat[0], wlat[1], wlat[2], wlat[3]);

        // normalizer S[j] via wave butterfly over s (static indices)
        float p[NJ];
#pragma unroll
        for (int lo = 0; lo < 4; ++lo)
#pragma unroll
            for (int la = 0; la < 4; ++la)
                p[lo * 4 + la] = wlon[lo] * wlat[la];
#pragma unroll
        for (int j = 0; j < NJ; ++j) {
            float t = p[j];
#pragma unroll
            for (int off = 1; off < 64; off <<= 1)
                t += __shfl_xor(t, off, 64);
            p[j] = t;
        }
        if (tid == 0) {
#pragma unroll
            for (int j = 0; j < NJ; ++j)
                s_sinv[j] = 1.0f / p[j];
        }
    }
    __syncthreads();   // also drains batch-1 loads (vmcnt(0)) under phase 1

    // ---------------- phase 2: FMA (wave = v) ----------------
    const float4* wl4 = reinterpret_cast<const float4*>(&s_wlon[0][0]);
    const float4* wt4 = reinterpret_cast<const float4*>(&s_wlat[0][0]);

    float acc0[NJ], acc1[NJ];
#pragma unroll
    for (int j = 0; j < NJ; ++j) { acc0[j] = 0.0f; acc1[j] = 0.0f; }

    if (xb) {
        // batch 2 issued first: latency hides under FMA on batch 1
        const unsigned int* xp = (const unsigned int*)x + base;
        unsigned int ub[8];
#pragma unroll
        for (int it = 0; it < 8; ++it)
            ub[it] = xp[(size_t)(4 * (it + 8) + sh) * 64];

#pragma unroll
        for (int it = 0; it < 16; ++it) {
            const unsigned int u = (it < 8) ? ua[it] : ub[it - 8];
            const int s = 4 * it + sh;
            union { unsigned int i; float fl; } u0, u1;
            u0.i = u << 16;
            u1.i = u & 0xffff0000u;
            const float f0 = u0.fl, f1 = u1.fl;
            const float4 wl = wl4[s];
            const float4 wt = wt4[s];
            const float wlv[4] = { wl.x, wl.y, wl.z, wl.w };
            const float wtv[4] = { wt.x, wt.y, wt.z, wt.w };
            float t0[4], t1[4];
#pragma unroll
            for (int la = 0; la < 4; ++la) { t0[la] = f0 * wtv[la]; t1[la] = f1 * wtv[la]; }
#pragma unroll
            for (int lo = 0; lo < 4; ++lo)
#pragma unroll
                for (int la = 0; la < 4; ++la) {
                    acc0[lo * 4 + la] += wlv[lo] * t0[la];
                    acc1[lo * 4 + la] += wlv[lo] * t1[la];
                }
        }
    } else {
        const float2* xp = (const float2*)x + base;
        float2 fb[8];
#pragma unroll
        for (int it = 0; it < 8; ++it)
            fb[it] = xp[(size_t)(4 * (it + 8) + sh) * 64];

#pragma unroll
        for (int it = 0; it < 16; ++it) {
            const float2 xv = (it < 8) ? fa[it] : fb[it - 8];
            const int s = 4 * it + sh;
            const float f0 = xv.x, f1 = xv.y;
            const float4 wl = wl4[s];
            const float4 wt = wt4[s];
            const float wlv[4] = { wl.x, wl.y, wl.z, wl.w };
            const float wtv[4] = { wt.x, wt.y, wt.z, wt.w };
            float t0[4], t1[4];
#pragma unroll
            for (int la = 0; la < 4; ++la) { t0[la] = f0 * wtv[la]; t1[la] = f1 * wtv[la]; }
#pragma unroll
            for (int lo = 0; lo < 4; ++lo)
#pragma unroll
                for (int la = 0; la < 4; ++la) {
                    acc0[lo * 4 + la] += wlv[lo] * t0[la];
                    acc1[lo * 4 + la] += wlv[lo] * t1[la];
                }
        }
    }

    // s-reduction over sh (lane bits 4,5) -- static indices only
#pragma unroll
    for (int j = 0; j < NJ; ++j) {
        float a = acc0[j], b = acc1[j];
        a += __shfl_xor(a, 16, 64);
        a += __shfl_xor(a, 32, 64);
        b += __shfl_xor(b, 16, 64);
        b += __shfl_xor(b, 32, 64);
        acc0[j] = a; acc1[j] = b;
    }

    // ---------------- epilogue: normalize, store f32 ----------------
    // sh==0 lanes store all 16 j (STATIC loop); 128 B contiguous per j.
    if (sh == 0) {
        float2* op = reinterpret_cast<float2*>(out);
#pragma unroll
        for (int j = 0; j < NJ; ++j) {
            const float si = s_sinv[j];
            // out float2 index = ((win*4 + v)*16 + j)*16 + c2
            op[((size_t)(win * 4 + v) * NJ + j) * 16 + c2] =
                make_float2(acc0[j] * si, acc1[j] * si);
        }
    }
}

extern "C" void kernel_launch(void* const* d_in, const int* in_sizes, int n_in,
                              void* d_out, int out_size, void* d_ws, size_t ws_size,
                              hipStream_t stream) {
    dim3 grid(NWIN);       // one window per block, 4 v-waves per block
    dim3 block(256);
    gauss_agg_kernel<<<grid, block, 0, stream>>>(
        d_in[0], d_in[1], d_in[2], d_in[3], d_in[4], d_in[5],
        (float*)d_out);
}